// Round 2
// baseline (459.224 us; speedup 1.0000x reference)
//
#include <hip/hip_runtime.h>

#define NL 16384          // row length
#define NB 64             // rows = blocks
#define NT 1024           // threads per block (16 waves = 4 waves/SIMD)
#define NC (NL / NT)      // 16 elements per thread == bits in the peak mask
#define NW (NT / 64)      // 16 waves
#define N_ITER 12
#define N_IMFS 6

#pragma clang fp contract(off)   // everything unfused EXCEPT the explicit fmaf

#define HSZ (NL + (NL >> 5))   // +1 float per 32: 2-way-max banking (free)
__device__ __forceinline__ int physi(int i) { return i + (i >> 5); }

#define FMAXV 3.402823466e38f

// Frozen bit-exact semantics (certified R9/R11, absmax 0.0).
// R12: NT 512->1024 (occupancy 6->12%), dur 283->251us but VALUBusy flat ->
// throughput-bound on the shared DS pipe, not latency-bound.
// R13: DS-pipe diet, arithmetic unchanged:
//  - h lives in VGPRs (hr[16]) across A->C->subtract; LDS h only written back
//    (4x b128) after subtract for neighbor boundaries + envelope gathers.
//  - meanb LDS buffer eliminated (mean in regs; subtract = register math).
//  - 4 of the 7 wave prefix-scans (6-step ds_bpermute each) replaced by
//    __ballot + 1 dynamic shfl each (identical values: nearest lane with a
//    peak). Mx/Mn scans moved behind the rare (totU<2||totL<2) uniform branch.
//  - vl/wl envelope endpoint gathers rolled in registers (own-chunk peaks are
//    already in hr); only the carry-in gather touches LDS.
// All value-path expressions, f64 sum orders, and decision protocol identical.
__global__ __launch_bounds__(NT, 4) void emd_main(
    const float* __restrict__ x, float* __restrict__ out,
    unsigned* cnt, double* sdsl, double* flsl) {
  __shared__ float h[HSZ];        // 67584 B (only big LDS buffer now)
  __shared__ int wLU[NW], wLL[NW], wNU[NW], wNL[NW];
  __shared__ float wMx[NW], wMn[NW];
  __shared__ unsigned wCT[NW];
  __shared__ int eLU[NW], eLL[NW], eNU[NW], eNL[NW];
  __shared__ float eMx[NW], eMn[NW];
  __shared__ unsigned sTot;
  __shared__ double tA[NW], tB[NW], tC[NW], tD[NW];
  __shared__ int sFlag;

  const int t = threadIdx.x;
  const int lane = t & 63;
  const int wv = t >> 6;
  const int row = blockIdx.x;
  const int base = t * NC;
  const float* xr = x + (size_t)row * NL;
  float* res = out + (size_t)N_IMFS * NB * NL + (size_t)row * NL;

  float hr[NC];   // register-resident h (always == LDS h after each barrier)

  // init: h = x row (regs + LDS, swizzled); res slab of d_out = x
  #pragma unroll
  for (int q = 0; q < NC / 4; q++) {
    int i0 = base + q * 4;
    float4 v = *(const float4*)&xr[i0];
    hr[q * 4 + 0] = v.x; hr[q * 4 + 1] = v.y;
    hr[q * 4 + 2] = v.z; hr[q * 4 + 3] = v.w;
    *(float4*)&h[physi(i0)] = v;
    *(float4*)&res[i0] = v;
  }
  __syncthreads();

  unsigned ep = 0;
  bool done = false;

  for (int k = 0; k < N_IMFS; k++) {
    float* outk = out + (size_t)k * NB * NL + (size_t)row * NL;
    if (done) {  // globally-uniform skip (no barriers)
      #pragma unroll
      for (int q = 0; q < NC / 4; q++)
        *(float4*)&outk[base + q * 4] = make_float4(0.f, 0.f, 0.f, 0.f);
      continue;
    }

    // ---------------- sifting ----------------
    for (int it = 0; it < N_ITER; it++) {
      // pass A: rolling walk over registers -> peak masks + chunk summaries
      unsigned mU = 0, mL = 0;
      int lmU = -1, lmL = -1, cU = 0, cL = 0;
      float rmx = -FMAXV, rmn = FMAXV;
      {
        float hm = (base > 0) ? h[physi(base - 1)] : 0.0f;   // neighbor (LDS)
        #pragma unroll
        for (int j = 0; j < NC; j++) {
          int i = base + j;
          float hc = hr[j];
          float hp = (j + 1 < NC) ? hr[j + 1]
                                  : ((i + 1 < NL) ? h[physi(i + 1)] : 0.0f);
          bool in = (i > 0) && (i + 1 < NL);
          if (in && hm < hc && hc > hp) { mU |= (1u << j); lmU = i; cU++; }
          if (in && hm > hc && hc < hp) { mL |= (1u << j); lmL = i; cL++; }
          rmx = fmaxf(rmx, hc);
          rmn = fminf(rmn, hc);
          hm = hc;
        }
      }
      int fpU = mU ? (base + __ffs(mU) - 1) : NL;   // first own peak
      int fpL = mL ? (base + __ffs(mL) - 1) : NL;
      unsigned long long bUm = __ballot(mU != 0);
      unsigned long long bLm = __ballot(mL != 0);
      // wave summaries: owning lane stores directly (no scans)
      {
        int s;
        s = bUm ? (63 - __clzll((long long)bUm)) : 0;
        if (lane == s) wLU[wv] = bUm ? lmU : -1;
        s = bLm ? (63 - __clzll((long long)bLm)) : 0;
        if (lane == s) wLL[wv] = bLm ? lmL : -1;
        s = bUm ? (__ffsll(bUm) - 1) : 0;
        if (lane == s) wNU[wv] = bUm ? fpU : NL;
        s = bLm ? (__ffsll(bLm) - 1) : 0;
        if (lane == s) wNL[wv] = bLm ? fpL : NL;
      }
      // block peak-count totals (reduce only; same pairwise order as before)
      unsigned ict = ((unsigned)cU << 16) | (unsigned)cL;
      #pragma unroll
      for (int o = 1; o < 64; o <<= 1) {
        unsigned cc = __shfl_down(ict, o, 64);
        if (lane + o < 64) ict += cc;
      }
      if (lane == 0) wCT[wv] = ict;
      __syncthreads();
      if (t == 0) {  // 16-entry serial combine -> exclusive wave carries
        int aLU = -1, aLL = -1; unsigned tt = 0;
        for (int w = 0; w < NW; w++) {
          eLU[w] = aLU; aLU = max(aLU, wLU[w]);
          eLL[w] = aLL; aLL = max(aLL, wLL[w]);
          tt += wCT[w];
        }
        int aNU = NL, aNL = NL;
        for (int w = NW - 1; w >= 0; w--) {
          eNU[w] = aNU; aNU = min(aNU, wNU[w]);
          eNL[w] = aNL; aNL = min(aNL, wNL[w]);
        }
        sTot = tt;
      }
      __syncthreads();
      const unsigned tot = sTot;
      const int totU = (int)(tot >> 16), totL = (int)(tot & 0xffffu);

      // per-thread carries via ballot bit-ops + one dynamic shuffle each
      unsigned long long belowU = bUm & ((1ull << lane) - 1ull);
      unsigned long long belowL = bLm & ((1ull << lane) - 1ull);
      unsigned long long aboveU = (lane == 63) ? 0ull : (bUm & (~0ull << (lane + 1)));
      unsigned long long aboveL = (lane == 63) ? 0ull : (bLm & (~0ull << (lane + 1)));
      int slU = belowU ? (63 - __clzll((long long)belowU)) : 0;
      int slL = belowL ? (63 - __clzll((long long)belowL)) : 0;
      int snU = aboveU ? (__ffsll(aboveU) - 1) : 0;
      int snL = aboveL ? (__ffsll(aboveL) - 1) : 0;
      int gU  = __shfl(lmU, slU, 64);
      int gL  = __shfl(lmL, slL, 64);
      int gNU = __shfl(fpU, snU, 64);
      int gNL = __shfl(fpL, snL, 64);
      const int clU = belowU ? gU  : eLU[wv];
      const int clL = belowL ? gL  : eLL[wv];
      const int cnU = aboveU ? gNU : eNU[wv];
      const int cnL = aboveL ? gNL : eNL[wv];

      // Mx/Mn prefix carries only needed for the <2-peaks fallback (rare);
      // tot is block-uniform so the branch (and its barriers) is uniform.
      float crx = -FMAXV, crn = FMAXV;
      if (totU < 2 || totL < 2) {
        float iMx = rmx, iMn = rmn;
        #pragma unroll
        for (int o = 1; o < 64; o <<= 1) {
          float fa = __shfl_up(iMx, o, 64);
          float fb = __shfl_up(iMn, o, 64);
          if (lane >= o) { iMx = fmaxf(iMx, fa); iMn = fminf(iMn, fb); }
        }
        if (lane == 63) { wMx[wv] = iMx; wMn[wv] = iMn; }
        __syncthreads();
        if (t == 0) {
          float aMx = -FMAXV, aMn = FMAXV;
          for (int w = 0; w < NW; w++) {
            eMx[w] = aMx; aMx = fmaxf(aMx, wMx[w]);
            eMn[w] = aMn; aMn = fminf(aMn, wMn[w]);
          }
        }
        __syncthreads();
        float pMx = __shfl_up(iMx, 1, 64); if (lane == 0) pMx = -FMAXV;
        float pMn = __shfl_up(iMn, 1, 64); if (lane == 0) pMn = FMAXV;
        crx = fmaxf(eMx[wv], pMx);
        crn = fminf(eMn[wv], pMn);
      }

      // pass C: envelopes + mean (frozen f32 ladder). vl/wl roll in registers;
      // vr/wr cached LDS gathers; mean kept in registers.
      float mr[NC];
      double pm2 = 0.0, ph2 = 0.0;
      {
        float rx = crx, rn = crn;
        int curLU = clU, curLL = clL;
        float vl = h[physi(clU < 0 ? 0 : clU)];   // carry-in gathers (1 each)
        float wl = h[physi(clL < 0 ? 0 : clL)];
        int gB = -0x7fffffff, gD = -0x7fffffff;
        float vr = 0.0f, wr = 0.0f;
        #pragma unroll
        for (int j = 0; j < NC; j++) {
          int i = base + j;
          float hc = hr[j];
          rx = fmaxf(rx, hc);
          rn = fminf(rn, hc);
          if ((mU >> j) & 1u) { curLU = i; vl = hc; }   // own peak: value in reg
          if ((mL >> j) & 1u) { curLL = i; wl = hc; }
          int lU = curLU, lL = curLL;
          unsigned highm = 0xFFFFFFFFu << j;         // bits >= j
          unsigned a;
          a = mU & highm; int nUv = a ? (base + __ffs(a) - 1) : cnU;
          a = mL & highm; int nLv = a ? (base + __ffs(a) - 1) : cnL;
          if (nUv != gB) { gB = nUv; vr = h[physi(nUv >= NL ? NL - 1 : nUv)]; }
          if (nLv != gD) { gD = nLv; wr = h[physi(nLv >= NL ? NL - 1 : nLv)]; }
          int den = nUv - lU;
          float fracU = (float)(i - lU) / (float)(den > 0 ? den : 1);
          float envU = (den > 0) ? __builtin_fmaf(fracU, vr - vl, vl) : vl;
          if (lU < 0) envU = vr;
          if (nUv >= NL) envU = vl;
          if (totU < 2) envU = rx;
          int den2 = nLv - lL;
          float fracL = (float)(i - lL) / (float)(den2 > 0 ? den2 : 1);
          float envL = (den2 > 0) ? __builtin_fmaf(fracL, wr - wl, wl) : wl;
          if (lL < 0) envL = wr;
          if (nLv >= NL) envL = wl;
          if (totL < 2) envL = rn;
          float mn = 0.5f * (envU + envL);
          mr[j] = mn;
          pm2 += (double)mn * (double)mn;
          ph2 += (double)hc * (double)hc;
        }
      }
      // fused block reduction of (pm2, ph2): wave shuffle, publish, t0 combines
      #pragma unroll
      for (int o = 1; o < 64; o <<= 1) {
        double a = __shfl_down(pm2, o, 64);
        double b = __shfl_down(ph2, o, 64);
        if (lane + o < 64) { pm2 += a; ph2 += b; }
      }
      if (lane == 0) { tA[wv] = pm2; tB[wv] = ph2; }
      // ---- grid barrier + convergence decision ----
      ep++;
      __syncthreads();   // orders tA/tB before t0 reads
      if (t == 0) {
        double sA = 0.0, sB = 0.0;
        for (int w = 0; w < NW; w++) { sA += tA[w]; sB += tB[w]; }
        atomicAdd(&sdsl[(k * N_ITER + it) * 2 + 0], sA);
        atomicAdd(&sdsl[(k * N_ITER + it) * 2 + 1], sB);
        __hip_atomic_fetch_add(cnt, 1u, __ATOMIC_ACQ_REL, __HIP_MEMORY_SCOPE_AGENT);
        unsigned tgt = ep * gridDim.x;
        while (__hip_atomic_load(cnt, __ATOMIC_ACQUIRE, __HIP_MEMORY_SCOPE_AGENT) < tgt)
          __builtin_amdgcn_s_sleep(1);
        double m2 = __hip_atomic_load(&sdsl[(k * N_ITER + it) * 2 + 0],
                                      __ATOMIC_RELAXED, __HIP_MEMORY_SCOPE_AGENT);
        double h2 = __hip_atomic_load(&sdsl[(k * N_ITER + it) * 2 + 1],
                                      __ATOMIC_RELAXED, __HIP_MEMORY_SCOPE_AGENT);
        sFlag = (m2 / (h2 + 1e-8) < 0.05) ? 1 : 0;
      }
      __syncthreads();
      if (sFlag) break;   // converged: h frozen (JAX done-latch semantics)
      // subtract in registers, then write back h -> LDS (float4, swizzle-safe)
      #pragma unroll
      for (int j = 0; j < NC; j++) hr[j] -= mr[j];
      #pragma unroll
      for (int q = 0; q < NC / 4; q++) {
        int i0 = base + q * 4;
        *(float4*)&h[physi(i0)] = make_float4(hr[q * 4 + 0], hr[q * 4 + 1],
                                              hr[q * 4 + 2], hr[q * 4 + 3]);
      }
      __syncthreads();
    }

    // ------------- flatness test + outputs (f32 values, f64 sums) -------------
    float rv[NC];
    #pragma unroll
    for (int q = 0; q < NC / 4; q++) {
      float4 v = *(const float4*)&res[base + q * 4];
      rv[q * 4 + 0] = v.x; rv[q * 4 + 1] = v.y;
      rv[q * 4 + 2] = v.z; rv[q * 4 + 3] = v.w;
    }
    double s1 = 0.0, s2 = 0.0, s3 = 0.0, s4 = 0.0;
    {
      float rb = 0.0f;   // res-h at base+NC (next thread's first element)
      if (base + NC < NL) rb = res[base + NC] - h[physi(base + NC)];
      float rc = rv[0] - hr[0];
      #pragma unroll
      for (int j = 0; j < NC; j++) {
        int i = base + j;
        s1 += (double)rc;
        s2 += (double)rc * (double)rc;
        if (i + 1 < NL) {
          float rnx = (j + 1 < NC) ? (rv[j + 1] - hr[j + 1]) : rb;
          float d = rnx - rc;
          s3 += (double)d;
          s4 += (double)d * (double)d;
          rc = rnx;
        }
      }
    }
    #pragma unroll
    for (int o = 1; o < 64; o <<= 1) {
      double a = __shfl_down(s1, o, 64);
      double b = __shfl_down(s2, o, 64);
      double c = __shfl_down(s3, o, 64);
      double d = __shfl_down(s4, o, 64);
      if (lane + o < 64) { s1 += a; s2 += b; s3 += c; s4 += d; }
    }
    if (lane == 0) { tA[wv] = s1; tB[wv] = s2; tC[wv] = s3; tD[wv] = s4; }
    __syncthreads();   // orders publishes AND all cross-thread h/res reads above
    if (t == 0) {
      double S1 = 0.0, S2 = 0.0, S3 = 0.0, S4 = 0.0;
      for (int w = 0; w < NW; w++) { S1 += tA[w]; S2 += tB[w]; S3 += tC[w]; S4 += tD[w]; }
      atomicAdd(&flsl[k * 4 + 0], S1);
      atomicAdd(&flsl[k * 4 + 1], S2);
      atomicAdd(&flsl[k * 4 + 2], S3);
      atomicAdd(&flsl[k * 4 + 3], S4);
    }
    // outputs: IMF k = h; res -= h; h <- new res (regs + LDS)
    #pragma unroll
    for (int q = 0; q < NC / 4; q++) {
      int i0 = base + q * 4;
      float4 hv = make_float4(hr[q * 4 + 0], hr[q * 4 + 1],
                              hr[q * 4 + 2], hr[q * 4 + 3]);
      float4 rq = make_float4(rv[q * 4 + 0] - hv.x, rv[q * 4 + 1] - hv.y,
                              rv[q * 4 + 2] - hv.z, rv[q * 4 + 3] - hv.w);
      *(float4*)&outk[i0] = hv;
      *(float4*)&res[i0] = rq;
      *(float4*)&h[physi(i0)] = rq;
      hr[q * 4 + 0] = rq.x; hr[q * 4 + 1] = rq.y;
      hr[q * 4 + 2] = rq.z; hr[q * 4 + 3] = rq.w;
    }
    // ---- grid barrier + flatness decision ----
    ep++;
    __syncthreads();
    if (t == 0) {
      __hip_atomic_fetch_add(cnt, 1u, __ATOMIC_ACQ_REL, __HIP_MEMORY_SCOPE_AGENT);
      unsigned tgt = ep * gridDim.x;
      while (__hip_atomic_load(cnt, __ATOMIC_ACQUIRE, __HIP_MEMORY_SCOPE_AGENT) < tgt)
        __builtin_amdgcn_s_sleep(1);
      double S1 = __hip_atomic_load(&flsl[k * 4 + 0], __ATOMIC_RELAXED, __HIP_MEMORY_SCOPE_AGENT);
      double S2 = __hip_atomic_load(&flsl[k * 4 + 1], __ATOMIC_RELAXED, __HIP_MEMORY_SCOPE_AGENT);
      double S3 = __hip_atomic_load(&flsl[k * 4 + 2], __ATOMIC_RELAXED, __HIP_MEMORY_SCOPE_AGENT);
      double S4 = __hip_atomic_load(&flsl[k * 4 + 3], __ATOMIC_RELAXED, __HIP_MEMORY_SCOPE_AGENT);
      double nr = (double)NB * (double)NL;
      double nd = (double)NB * (double)(NL - 1);
      double varr = (S2 - S1 * S1 / nr) / (nr - 1.0);
      double vard = (S4 - S3 * S3 / nd) / (nd - 1.0);
      sFlag = (vard < 0.05 * varr) ? 1 : 0;
    }
    __syncthreads();
    done = done || (sFlag != 0);
  }
}

extern "C" void kernel_launch(void* const* d_in, const int* in_sizes, int n_in,
                              void* d_out, int out_size, void* d_ws, size_t ws_size,
                              hipStream_t stream) {
  const float* x = (const float*)d_in[0];
  float* out = (float*)d_out;
  // ws layout: [0] barrier counter; [256] sd slots (6*12*2 dbl); [1408] flat slots (6*4 dbl)
  size_t zb = ws_size < 4096 ? ws_size : 4096;
  hipMemsetAsync(d_ws, 0, zb, stream);
  unsigned* cnt = (unsigned*)d_ws;
  double* sdsl = (double*)((char*)d_ws + 256);
  double* flsl = (double*)((char*)d_ws + 256 + (size_t)N_IMFS * N_ITER * 2 * 8);
  hipLaunchKernelGGL(emd_main, dim3(NB), dim3(NT), 0, stream, x, out, cnt, sdsl, flsl);
}